// Round 1
// baseline (172.706 us; speedup 1.0000x reference)
//
#include <hip/hip_runtime.h>

// B=256, T=256, DM=384, DK=DV=64.
// k0: W -> Wt bf16 [192 cols][384 k]  (coalesced-output transpose)
// k1: FUSED, one block/batch (1024 thr = 16 waves):
//   Phase 1 (QKV GEMM): wave w owns token rows [16w,16w+16) x all 192 cols.
//     A (x fp32) -> software-pipelined into VGPRs: next mega's 6 float4 loads
//     issued right after the barrier (overlapped with current mega's MFMAs),
//     converted to bf16 AFTER compute so the cvt never waits on HBM.
//     B (Wt bf16) -> LDS via global_load_lds in 4 double-buffered mega-chunks
//     of 3 k-chunks (36.9KB); only 4 barriers, barrier-free inside a mega.
//   Phase 2: Q -> per-wave scratch (dead wb region), K -> sK, V^T -> sVT
//     (packed ds_write_b64).
//   Phase 3: S=QK^T with triangular wave skip; maskless-fused softmax (no
//     max-subtract: logits bounded, fp32 exp safe).
//   Phase 4: P via per-wave scratch (C->A layout), PV from LDS V^T.

typedef __attribute__((ext_vector_type(8))) short short8;
typedef __attribute__((ext_vector_type(4))) float floatx4;

__device__ inline unsigned short f2bf(float f) {
  union { float f; unsigned u; } v; v.f = f;
  unsigned r = v.u + 0x7FFFu + ((v.u >> 16) & 1u);  // RNE
  return (unsigned short)(r >> 16);
}

__device__ inline void glds16(const void* g, void* l) {
  __builtin_amdgcn_global_load_lds(
      (const __attribute__((address_space(1))) void*)g,
      (__attribute__((address_space(3))) void*)l, 16, 0, 0);
}

// ---------------- kernel 0: weight transpose/convert (output-indexed) -------
__global__ void wt_kernel(const float* __restrict__ wq, const float* __restrict__ wk,
                          const float* __restrict__ wv, unsigned short* __restrict__ wt) {
  int idx = blockIdx.x * 256 + threadIdx.x;      // enumerates OUTPUT [mat][n][k]
  if (idx >= 3 * 64 * 384) return;
  int mat = idx / (64 * 384);
  int rem = idx % (64 * 384);
  int n = rem / 384, k = rem % 384;
  const float* w = (mat == 0) ? wq : ((mat == 1) ? wk : wv);
  wt[idx] = f2bf(w[k * 64 + n]);
}

// ---------------- kernel 1: fused QKV + attention ----------------
__global__ __launch_bounds__(1024) void fused_kernel(
    const float* __restrict__ x, const unsigned short* __restrict__ wt,
    float* __restrict__ out) {
  // wb[buf][kc][192 cols][32 k] bf16: 36864B per buffer. Reused as scratch later.
  __shared__ __align__(16) unsigned short wb[2][3 * 192 * 32];  // 73728 B
  __shared__ __align__(16) unsigned short sK[256 * 72];         // 36864 B
  __shared__ __align__(16) unsigned short sVT[64 * 264];        // 33792 B

  int tid = threadIdx.x, lane = tid & 63, w = tid >> 6;
  int m = lane & 15, q = lane >> 4;
  int b = blockIdx.x;
  const float* xb = x + (size_t)b * 256 * 384;

  // stage one mega-chunk (3 k-chunks of 32) of Wt into wb[buf]: 36 x 1KB issues
  auto stage = [&](int mega, int buf) {
#pragma unroll
    for (int t = 0; t < 3; ++t) {
      int i = w + 16 * t;
      if (i < 36) {
        int kc = i / 12, sub = i % 12;
        int c = sub * 16 + (lane >> 2), g = lane & 3;
        glds16(wt + (size_t)c * 384 + (mega * 3 + kc) * 32 + g * 8,
               (void*)&wb[buf][kc * 6144 + sub * 512]);
      }
    }
  };

  floatx4 z = {0.f, 0.f, 0.f, 0.f};
  floatx4 acc[12];
#pragma unroll
  for (int nt = 0; nt < 12; ++nt) acc[nt] = z;

  // lane's x row base (covers the q*8 column offset once)
  const float* aw = xb + (size_t)(w * 16 + m) * 384 + q * 8;

  float4 fa[6];     // in-flight next-mega A (fp32)
  short8 cur[3];    // current-mega A fragments (bf16)

  // prologue: issue W stage for mega 0, issue+convert A for mega 0
  stage(0, 0);
#pragma unroll
  for (int kc = 0; kc < 3; ++kc) {
    fa[2 * kc]     = *(const float4*)(aw + kc * 32);
    fa[2 * kc + 1] = *(const float4*)(aw + kc * 32 + 4);
  }
#pragma unroll
  for (int kc = 0; kc < 3; ++kc) {
    float4 f0 = fa[2 * kc], f1 = fa[2 * kc + 1];
    short8 af;
    af[0] = (short)f2bf(f0.x); af[1] = (short)f2bf(f0.y);
    af[2] = (short)f2bf(f0.z); af[3] = (short)f2bf(f0.w);
    af[4] = (short)f2bf(f1.x); af[5] = (short)f2bf(f1.y);
    af[6] = (short)f2bf(f1.z); af[7] = (short)f2bf(f1.w);
    cur[kc] = af;
  }

#pragma unroll
  for (int mega = 0; mega < 4; ++mega) {
    int buf = mega & 1;
    __syncthreads();                    // wb[buf] staged; prior reads of buf^1 done
    if (mega < 3) {
      stage(mega + 1, buf ^ 1);
      // issue next mega's A loads NOW; they land under this mega's MFMAs
#pragma unroll
      for (int kc = 0; kc < 3; ++kc) {
        fa[2 * kc]     = *(const float4*)(aw + ((mega + 1) * 3 + kc) * 32);
        fa[2 * kc + 1] = *(const float4*)(aw + ((mega + 1) * 3 + kc) * 32 + 4);
      }
    }

#pragma unroll
    for (int kc = 0; kc < 3; ++kc) {
      const unsigned short* wbk = &wb[buf][kc * 6144];
      short8 af = cur[kc];
#pragma unroll
      for (int nt = 0; nt < 12; ++nt) {
        // granule = (4m+q) mod 8 -> uniform 8 lanes/group: conflict-free
        short8 bf = *(const short8*)&wbk[(nt * 16 + m) * 32 + q * 8];
        acc[nt] = __builtin_amdgcn_mfma_f32_16x16x32_bf16(af, bf, acc[nt], 0, 0, 0);
      }
    }

    if (mega < 3) {                     // convert landed A for next mega
#pragma unroll
      for (int kc = 0; kc < 3; ++kc) {
        float4 f0 = fa[2 * kc], f1 = fa[2 * kc + 1];
        short8 af;
        af[0] = (short)f2bf(f0.x); af[1] = (short)f2bf(f0.y);
        af[2] = (short)f2bf(f0.z); af[3] = (short)f2bf(f0.w);
        af[4] = (short)f2bf(f1.x); af[5] = (short)f2bf(f1.y);
        af[6] = (short)f2bf(f1.z); af[7] = (short)f2bf(f1.w);
        cur[kc] = af;
      }
    }
  }

  // ---------- epilogue: Q -> per-wave scratch (wb area), K -> sK, V^T -> sVT ----
  unsigned short* scr = &wb[0][0] + w * 1152;   // [16][72] bf16 per wave, 2304 B
#pragma unroll
  for (int nt = 0; nt < 8; ++nt) {
#pragma unroll
    for (int j = 0; j < 4; ++j) {
      unsigned short val = f2bf(acc[nt][j]);
      int lrow = q * 4 + j;                     // C-layout row within wave's 16
      if (nt < 4) scr[lrow * 72 + nt * 16 + m] = val;                  // Q
      else        sK[(w * 16 + lrow) * 72 + (nt - 4) * 16 + m] = val;  // K
    }
  }
#pragma unroll
  for (int nt = 8; nt < 12; ++nt) {             // V^T, packed 4 rows -> b64
    ushort4 pv;
    pv.x = f2bf(acc[nt][0]); pv.y = f2bf(acc[nt][1]);
    pv.z = f2bf(acc[nt][2]); pv.w = f2bf(acc[nt][3]);
    *(ushort4*)&sVT[((nt - 8) * 16 + m) * 264 + w * 16 + q * 4] = pv;
  }

  // Q fragments from own scratch (wave-local)
  short8 qf0 = *(const short8*)(scr + m * 72 + q * 8);
  short8 qf1 = *(const short8*)(scr + m * 72 + 32 + q * 8);

  __syncthreads();                              // sK, sVT visible to all waves

  // ---------- S = Q K^T (triangular: wave w needs col tiles nt <= w) ----------
  floatx4 sacc[16];
#pragma unroll
  for (int nt = 0; nt < 16; ++nt) {
    if (nt > w) continue;                       // wave-uniform skip
    short8 kb0 = *(const short8*)(sK + (nt * 16 + m) * 72 + q * 8);
    short8 kb1 = *(const short8*)(sK + (nt * 16 + m) * 72 + 32 + q * 8);
    floatx4 t = __builtin_amdgcn_mfma_f32_16x16x32_bf16(qf0, kb0, z, 0, 0, 0);
    sacc[nt] = __builtin_amdgcn_mfma_f32_16x16x32_bf16(qf1, kb1, t, 0, 0, 0);
  }

  // ---------- fused causal mask + softmax (no max-subtract) ----------
  const float CSC = 0.18033688011112042f;       // log2(e)/sqrt(64)
  float inv_[4];
  int rbase = w * 16 + q * 4;
#pragma unroll
  for (int j = 0; j < 4; ++j) {
    int rg = rbase + j;
    float sum = 0.f;
#pragma unroll
    for (int nt = 0; nt < 16; ++nt) {
      if (nt > w) continue;
      int col = nt * 16 + m;
      float p = (col <= rg) ? exp2f(sacc[nt][j] * CSC) : 0.f;
      sacc[nt][j] = p;
      sum += p;
    }
    sum += __shfl_xor(sum, 1);
    sum += __shfl_xor(sum, 2);
    sum += __shfl_xor(sum, 4);
    sum += __shfl_xor(sum, 8);
    inv_[j] = 1.f / sum;                        // diagonal term -> sum >= 1
  }

  // ---------- O = P V, chunked by 64 k-cols through per-wave scratch ----------
  floatx4 o[4];
#pragma unroll
  for (int vt = 0; vt < 4; ++vt) o[vt] = z;
#pragma unroll
  for (int c = 0; c < 4; ++c) {
    if (4 * c > w) continue;                    // chunk needed iff 64c <= 16w+15
#pragma unroll
    for (int t = 0; t < 4; ++t) {
      int nt = 4 * c + t;
#pragma unroll
      for (int j = 0; j < 4; ++j) {
        unsigned short pv = (nt <= w) ? f2bf(sacc[nt][j] * inv_[j]) : (unsigned short)0;
        scr[(q * 4 + j) * 72 + t * 16 + m] = pv;
      }
    }
    short8 pf0 = *(const short8*)(scr + m * 72 + q * 8);
    short8 pf1 = *(const short8*)(scr + m * 72 + 32 + q * 8);
#pragma unroll
    for (int vt = 0; vt < 4; ++vt) {
      short8 vb0 = *(const short8*)(sVT + (vt * 16 + m) * 264 + c * 64 + q * 8);
      short8 vb1 = *(const short8*)(sVT + (vt * 16 + m) * 264 + c * 64 + 32 + q * 8);
      o[vt] = __builtin_amdgcn_mfma_f32_16x16x32_bf16(pf0, vb0, o[vt], 0, 0, 0);
      o[vt] = __builtin_amdgcn_mfma_f32_16x16x32_bf16(pf1, vb1, o[vt], 0, 0, 0);
    }
  }

  // ---------- store O ----------
  float* op = out + ((size_t)b * 256 + w * 16) * 64;
#pragma unroll
  for (int vt = 0; vt < 4; ++vt)
#pragma unroll
    for (int j = 0; j < 4; ++j)
      op[(q * 4 + j) * 64 + vt * 16 + m] = o[vt][j];
}

extern "C" void kernel_launch(void* const* d_in, const int* in_sizes, int n_in,
                              void* d_out, int out_size, void* d_ws, size_t ws_size,
                              hipStream_t stream) {
  const float* x  = (const float*)d_in[0];
  const float* wq = (const float*)d_in[1];
  const float* wk = (const float*)d_in[2];
  const float* wv = (const float*)d_in[3];
  float* out = (float*)d_out;

  unsigned short* wt = (unsigned short*)d_ws;   // Wt bf16 [192][384] = 147456 B

  wt_kernel<<<288, 256, 0, stream>>>(wq, wk, wv, wt);
  fused_kernel<<<256, 1024, 0, stream>>>(x, wt, out);
}